// Round 8
// baseline (664.900 us; speedup 1.0000x reference)
//
#include <hip/hip_runtime.h>
#include <hip/hip_cooperative_groups.h>

namespace cg = cooperative_groups;

#define DEV __device__ __forceinline__

typedef __attribute__((ext_vector_type(8))) short sv8;   // 8 x bf16 bits
typedef __attribute__((ext_vector_type(4))) short sv4;
typedef __attribute__((ext_vector_type(4))) float f32x4;

// ---- bf16 helpers (bit-level, round-to-nearest-even) ----
DEV short f2bf(float f) {
  unsigned u = __float_as_uint(f);
  unsigned r = (u + 0x7fffu + ((u >> 16) & 1u)) >> 16;
  return (short)r;
}
DEV float bf2f(short s) {
  return __uint_as_float(((unsigned)(unsigned short)s) << 16);
}

// ---- async global -> LDS, 16B per lane. LDS dest = wave-uniform base + lane*16 ----
DEV void gload16(const void* g, void* l) {
  __builtin_amdgcn_global_load_lds((const __attribute__((address_space(1))) void*)g,
                                   (__attribute__((address_space(3))) void*)l, 16, 0, 0);
}

struct MegaArgs {
  const float *x, *ctx, *Wq, *Wk, *Wv1, *ln_g, *ln_b, *Wconv, *Wout;
  short *x_bf, *ctx_bf, *wq_bf, *wk_bf, *wv1_bf, *wout_bf;
  short *q_bf, *k_bf, *mid_bf, *op_bf;
  float *attn, *tbuf, *part, *out;
};

// ================= shared DEV bodies (identical math to the passing round-5) ==========

// ---- NT GEMM tile: C[M,N] = A[M,K]*B[N,K]^T, 128x128 tile, BK=32, 2-phase dbuf ----
template <int MODE, int SPLITK>   // MODE: 0 = f32 store, 1 = bf16 store
DEV void gemm_tile(char* smem, const short* __restrict__ A, const short* __restrict__ B,
                   void* __restrict__ C, int M, int N, int K,
                   int bm, int bn, int ks) {
  short* As = (short*)smem;          // [2][4096]
  short* Bs = As + 8192;             // [2][4096]
  const int tid = threadIdx.x;
  const int wave = tid >> 6, lane = tid & 63;
  const int wr = wave >> 1, wc = wave & 1;
  const int row0 = bm * 128, col0 = bn * 128;
  const int rsel = lane & 15;
  const int Am = M - 1, Bm = N - 1;
  const int lr = lane >> 2;
  const int c8 = ((lane & 3) ^ ((lane >> 2) & 3)) * 8;  // inverse-swizzled source slot
  const int Ksl = K / SPLITK;
  const int kbase = ks * Ksl;
  const int nt = Ksl / 32;

  const f32x4 z = {0.f, 0.f, 0.f, 0.f};
  f32x4 acc[4][4];
#pragma unroll
  for (int m = 0; m < 4; ++m)
#pragma unroll
    for (int n = 0; n < 4; ++n) acc[m][n] = z;

  auto stage = [&](int t, int buf) {
    int k0 = kbase + t * 32;
#pragma unroll
    for (int s = 0; s < 2; ++s) {
      int chunk = s * 4 + wave;            // wave-uniform LDS chunk
      int rr = chunk * 16 + lr;
      int gr = row0 + rr; if (gr > Am) gr = Am;
      gload16(A + (size_t)gr * K + k0 + c8, As + buf * 4096 + chunk * 512);
      int gc = col0 + rr; if (gc > Bm) gc = Bm;
      gload16(B + (size_t)gc * K + k0 + c8, Bs + buf * 4096 + chunk * 512);
    }
  };

  stage(0, 0);
  __syncthreads();
  const int ko = (((lane >> 4) ^ (rsel & 3)) * 8);  // swizzled read slot

  for (int t = 0; t < nt; ++t) {
    int cur = t & 1;
    if (t + 1 < nt) stage(t + 1, cur ^ 1);
    sv8 a[4], b[4];
#pragma unroll
    for (int m = 0; m < 4; ++m)
      a[m] = *(const sv8*)(As + cur * 4096 + (wr * 64 + m * 16 + rsel) * 32 + ko);
#pragma unroll
    for (int n = 0; n < 4; ++n)
      b[n] = *(const sv8*)(Bs + cur * 4096 + (wc * 64 + n * 16 + rsel) * 32 + ko);
#pragma unroll
    for (int m = 0; m < 4; ++m)
#pragma unroll
      for (int n = 0; n < 4; ++n)
        acc[m][n] = __builtin_amdgcn_mfma_f32_16x16x32_bf16(a[m], b[n], acc[m][n], 0, 0, 0);
    __syncthreads();
  }

  const int cc = lane & 15, cr = (lane >> 4) * 4;
#pragma unroll
  for (int m = 0; m < 4; ++m)
#pragma unroll
    for (int n = 0; n < 4; ++n) {
      int c = col0 + wc * 64 + n * 16 + cc;
#pragma unroll
      for (int j = 0; j < 4; ++j) {
        int r = row0 + wr * 64 + m * 16 + cr + j;
        if (r < M && c < N) {
          float v = acc[m][n][j];
          if (MODE == 1) ((short*)C)[(size_t)r * N + c] = f2bf(v);
          else           ((float*)C)[(size_t)r * N + c] = v;
        }
      }
    }
}

DEV void ln_body(int row, short* __restrict__ mid, const float* __restrict__ g,
                 const float* __restrict__ bb, char* smem) {
  float* rs = (float*)smem;
  float* rss = rs + 4;
  short* p = mid + (size_t)row * 4096;
  const int tid = threadIdx.x;
  sv8 v0 = *(const sv8*)(p + tid * 16);
  sv8 v1 = *(const sv8*)(p + tid * 16 + 8);
  float x[16];
#pragma unroll
  for (int j = 0; j < 8; ++j) { x[j] = bf2f(v0[j]); x[8 + j] = bf2f(v1[j]); }
  float s = 0.f, ss = 0.f;
#pragma unroll
  for (int j = 0; j < 16; ++j) { s += x[j]; ss += x[j] * x[j]; }
#pragma unroll
  for (int off = 32; off; off >>= 1) { s += __shfl_xor(s, off); ss += __shfl_xor(ss, off); }
  if ((tid & 63) == 0) { rs[tid >> 6] = s; rss[tid >> 6] = ss; }
  __syncthreads();
  float S = rs[0] + rs[1] + rs[2] + rs[3];
  float SS = rss[0] + rss[1] + rss[2] + rss[3];
  __syncthreads();
  const float inv_n = 1.0f / 4096.0f;
  float mu = S * inv_n;
  float var = SS * inv_n - mu * mu;
  float rstd = rsqrtf(var + 1e-5f);
  const float4* g4 = (const float4*)(g + tid * 16);
  const float4* b4 = (const float4*)(bb + tid * 16);
  float y[16];
#pragma unroll
  for (int i = 0; i < 4; ++i) {
    float4 gg = g4[i], bv = b4[i];
    y[i * 4 + 0] = (x[i * 4 + 0] - mu) * rstd * gg.x + bv.x;
    y[i * 4 + 1] = (x[i * 4 + 1] - mu) * rstd * gg.y + bv.y;
    y[i * 4 + 2] = (x[i * 4 + 2] - mu) * rstd * gg.z + bv.z;
    y[i * 4 + 3] = (x[i * 4 + 3] - mu) * rstd * gg.w + bv.w;
  }
  sv8 o0, o1;
#pragma unroll
  for (int j = 0; j < 8; ++j) { o0[j] = f2bf(y[j]); o1[j] = f2bf(y[8 + j]); }
  *(sv8*)(p + tid * 16) = o0;
  *(sv8*)(p + tid * 16 + 8) = o1;
}

DEV void attn_body(int bh, const short* __restrict__ qb, const short* __restrict__ kb,
                   float* __restrict__ attn, char* smem) {
  float (*wred)[64] = (float(*)[64])smem;
  const int b = bh / 6, h = bh % 6;
  const int tid = threadIdx.x, wave = tid >> 6, lane = tid & 63;
  const int rsel = lane & 15, koff = (lane >> 4) * 8;
  const int rhi = (lane >> 4) * 4;

  const f32x4 z = {0.f, 0.f, 0.f, 0.f};
  f32x4 acc[4][5];
#pragma unroll
  for (int m = 0; m < 4; ++m)
#pragma unroll
    for (int i = 0; i < 5; ++i) acc[m][i] = z;

#pragma unroll
  for (int k0 = 0; k0 < 128; k0 += 32) {
    sv8 a[4];
#pragma unroll
    for (int m = 0; m < 4; ++m)
      a[m] = *(const sv8*)(qb + (size_t)(b * 64 + m * 16 + rsel) * 768 + h * 128 + k0 + koff);
#pragma unroll
    for (int i = 0; i < 5; ++i) {
      int nf = wave + i * 4;
      if (nf > 16) continue;
      int j = nf * 16 + rsel; if (j > 256) j = 256;
      sv8 bf = *(const sv8*)(kb + (size_t)(b * 257 + j) * 768 + h * 128 + k0 + koff);
#pragma unroll
      for (int m = 0; m < 4; ++m)
        acc[m][i] = __builtin_amdgcn_mfma_f32_16x16x32_bf16(a[m], bf, acc[m][i], 0, 0, 0);
    }
  }
  const float S2 = 0.08838834764831845f;  // 1/sqrt(128)
#pragma unroll
  for (int m = 0; m < 4; ++m)
#pragma unroll
    for (int i = 0; i < 5; ++i) {
      int col = (wave + i * 4) * 16 + rsel;
      bool valid = col < 257;
#pragma unroll
      for (int j = 0; j < 4; ++j)
        acc[m][i][j] = valid ? acc[m][i][j] * S2 : -1e30f;
    }
  float mx[4][4];
#pragma unroll
  for (int m = 0; m < 4; ++m)
#pragma unroll
    for (int j = 0; j < 4; ++j) {
      float pm = acc[m][0][j];
#pragma unroll
      for (int i = 1; i < 5; ++i) pm = fmaxf(pm, acc[m][i][j]);
      pm = fmaxf(pm, __shfl_xor(pm, 1));
      pm = fmaxf(pm, __shfl_xor(pm, 2));
      pm = fmaxf(pm, __shfl_xor(pm, 4));
      pm = fmaxf(pm, __shfl_xor(pm, 8));
      mx[m][j] = pm;
      if (rsel == 0) wred[wave][m * 16 + rhi + j] = pm;
    }
  __syncthreads();
#pragma unroll
  for (int m = 0; m < 4; ++m)
#pragma unroll
    for (int j = 0; j < 4; ++j) {
      int row = m * 16 + rhi + j;
      mx[m][j] = fmaxf(fmaxf(wred[0][row], wred[1][row]), fmaxf(wred[2][row], wred[3][row]));
    }
  __syncthreads();
  float inv[4][4];
#pragma unroll
  for (int m = 0; m < 4; ++m)
#pragma unroll
    for (int j = 0; j < 4; ++j) {
      float ps = 0.f;
#pragma unroll
      for (int i = 0; i < 5; ++i) {
        float e = __expf(acc[m][i][j] - mx[m][j]);
        acc[m][i][j] = e;
        ps += e;
      }
      ps += __shfl_xor(ps, 1);
      ps += __shfl_xor(ps, 2);
      ps += __shfl_xor(ps, 4);
      ps += __shfl_xor(ps, 8);
      if (rsel == 0) wred[wave][m * 16 + rhi + j] = ps;
    }
  __syncthreads();
  float* base = attn + (size_t)bh * 64 * 257;
#pragma unroll
  for (int m = 0; m < 4; ++m)
#pragma unroll
    for (int j = 0; j < 4; ++j) {
      int row = m * 16 + rhi + j;
      float tot = wred[0][row] + wred[1][row] + wred[2][row] + wred[3][row];
      inv[m][j] = 1.f / tot;
    }
  __syncthreads();
#pragma unroll
  for (int m = 0; m < 4; ++m)
#pragma unroll
    for (int i = 0; i < 5; ++i) {
      int nf = wave + i * 4;
      if (nf > 16) continue;
      int col = nf * 16 + rsel;
      if (col < 257) {
#pragma unroll
        for (int j = 0; j < 4; ++j)
          base[(size_t)(m * 16 + rhi + j) * 257 + col] = acc[m][i][j] * inv[m][j];
      }
    }
}

DEV void tk_body(int bq, char* smem, const float* __restrict__ attn,
                 const short* __restrict__ mid, float* __restrict__ t) {
  short (*ms)[64] = (short(*)[64])smem;              // 32896 B
  float (*as_)[257] = (float(*)[257])(smem + 32896); // 6168 B
  const int b = bq >> 6, q = bq & 63;
  const int tid = threadIdx.x;
  for (int lin = tid; lin < 257 * 8; lin += 256) {
    int j = lin >> 3, seg = (lin & 7) * 8;
    *(sv8*)(&ms[j][seg]) = *(const sv8*)(mid + (size_t)(b * 257 + j) * 4096 + q * 64 + seg);
  }
#pragma unroll
  for (int h = 0; h < 6; ++h)
    for (int j = tid; j < 257; j += 256)
      as_[h][j] = attn[((size_t)(b * 6 + h) * 64 + q) * 257 + j];
  __syncthreads();
  for (int idx = tid; idx < 384; idx += 256) {
    int h = idx >> 6, r = idx & 63;
    float s = 0.f;
#pragma unroll 4
    for (int j = 0; j < 257; ++j) s += as_[h][j] * bf2f(ms[j][r]);
    t[((size_t)(b * 6 + h) * 64 + q) * 64 + r] = s;
  }
  __syncthreads();
}

DEV void vproj_body(int q, int chunk, char* smem, const float* __restrict__ t,
                    const float* __restrict__ Wconv, short* __restrict__ op) {
  float (*ts)[64] = (float(*)[64])smem;
  const int tid = threadIdx.x;
  for (int lin = tid; lin < 48 * 64; lin += 256) {
    int bh = lin >> 6, r = lin & 63;
    ts[bh][r] = t[((size_t)bh * 64 + q) * 64 + r];
  }
  __syncthreads();
  const int d = chunk * 256 + tid;
  const int h = d >> 7;
  const float4* w4 = (const float4*)(Wconv + ((size_t)q * 768 + d) * 64);
  float acc[8] = {0.f, 0.f, 0.f, 0.f, 0.f, 0.f, 0.f, 0.f};
#pragma unroll
  for (int r4 = 0; r4 < 16; ++r4) {
    float4 w = w4[r4];
#pragma unroll
    for (int bb = 0; bb < 8; ++bb) {
      acc[bb] += w.x * ts[bb * 6 + h][r4 * 4 + 0];
      acc[bb] += w.y * ts[bb * 6 + h][r4 * 4 + 1];
      acc[bb] += w.z * ts[bb * 6 + h][r4 * 4 + 2];
      acc[bb] += w.w * ts[bb * 6 + h][r4 * 4 + 3];
    }
  }
#pragma unroll
  for (int bb = 0; bb < 8; ++bb)
    op[((size_t)(bb * 64 + q)) * 768 + d] = f2bf(acc[bb]);
  __syncthreads();
}

// ---- phase helpers shared by mega and fallback ----
DEV void phaseA(const MegaArgs& a, int gtid, int T) {
  for (int i = gtid; i < 1721856; i += T) {
    const float* s; short* d; int base;
    if      (i < 98304)   { s = a.x;    d = a.x_bf;    base = 0; }
    else if (i < 493056)  { s = a.ctx;  d = a.ctx_bf;  base = 98304; }
    else if (i < 640512)  { s = a.Wq;   d = a.wq_bf;   base = 493056; }
    else if (i < 787968)  { s = a.Wk;   d = a.wk_bf;   base = 640512; }
    else if (i < 1574400) { s = a.Wv1;  d = a.wv1_bf;  base = 787968; }
    else                  { s = a.Wout; d = a.wout_bf; base = 1574400; }
    int j = i - base;
    float4 v = ((const float4*)s)[j];
    sv4 o = { f2bf(v.x), f2bf(v.y), f2bf(v.z), f2bf(v.w) };
    ((sv4*)d)[j] = o;
  }
}
DEV void phaseB(const MegaArgs& a, char* smem, int tile) {
  const short *A_, *B_; short* C_; int M_, nb_, local;
  if (tile < 24)       { A_ = a.x_bf;   B_ = a.wq_bf;  C_ = a.q_bf;   M_ = 512;  nb_ = 6;  local = tile; }
  else if (tile < 126) { A_ = a.ctx_bf; B_ = a.wk_bf;  C_ = a.k_bf;   M_ = 2056; nb_ = 6;  local = tile - 24; }
  else                 { A_ = a.ctx_bf; B_ = a.wv1_bf; C_ = a.mid_bf; M_ = 2056; nb_ = 32; local = tile - 126; }
  gemm_tile<1, 1>(smem, A_, B_, C_, M_, nb_ * 128, 768, local / nb_, local % nb_, 0);
}
DEV void phaseC(const MegaArgs& a, char* smem, int item) {
  if (item < 48) attn_body(item, a.q_bf, a.k_bf, a.attn, smem);
  else           ln_body(item - 48, a.mid_bf, a.ln_g, a.ln_b, smem);
}
DEV void phaseF(const MegaArgs& a, char* smem, int it) {
  int ks = it & 7, t24 = it >> 3;
  gemm_tile<0, 8>(smem, a.op_bf, a.wout_bf, a.part + (size_t)ks * 393216,
                  512, 768, 768, t24 & 3, t24 >> 2, ks);
}
DEV void phaseG(const MegaArgs& a, int gtid, int T) {
  for (int i = gtid; i < 98304; i += T) {
    float4 s = ((const float4*)a.part)[i];
#pragma unroll
    for (int k = 1; k < 8; ++k) {
      float4 p = ((const float4*)(a.part + (size_t)k * 393216))[i];
      s.x += p.x; s.y += p.y; s.z += p.z; s.w += p.w;
    }
    ((float4*)a.out)[i] = s;
  }
}

// ================= cooperative mega-kernel (grid-size agnostic) =================
__global__ __launch_bounds__(256, 2) void mega(MegaArgs a) {
  __shared__ __align__(16) char smem[39104];
  cg::grid_group grid = cg::this_grid();
  const int bid = blockIdx.x, tid = threadIdx.x;
  const int G = gridDim.x;
  const int gtid = bid * 256 + tid;
  const int T = G * 256;

  phaseA(a, gtid, T);
  __threadfence(); grid.sync(); __threadfence();
  for (int tile = bid; tile < 670; tile += G) phaseB(a, smem, tile);
  __threadfence(); grid.sync(); __threadfence();
  for (int item = bid; item < 2104; item += G) phaseC(a, smem, item);
  __threadfence(); grid.sync(); __threadfence();
  for (int bq = bid; bq < 512; bq += G) tk_body(bq, smem, a.attn, a.mid_bf, a.tbuf);
  __threadfence(); grid.sync(); __threadfence();
  for (int it = bid; it < 192; it += G) vproj_body(it / 3, it % 3, smem, a.tbuf, a.Wconv, a.op_bf);
  __threadfence(); grid.sync(); __threadfence();
  for (int it = bid; it < 192; it += G) phaseF(a, smem, it);
  __threadfence(); grid.sync(); __threadfence();
  phaseG(a, gtid, T);
}

// ================= fallback: separate kernels (proven round-5 structure) ========
__global__ __launch_bounds__(256) void k_cvt(MegaArgs a) {
  phaseA(a, blockIdx.x * 256 + threadIdx.x, gridDim.x * 256);
}
__global__ __launch_bounds__(256) void k_gemm3(MegaArgs a) {
  __shared__ __align__(16) char smem[16384];
  phaseB(a, smem, blockIdx.x);
}
__global__ __launch_bounds__(256) void k_lnattn(MegaArgs a) {
  __shared__ __align__(16) char smem[1024];
  phaseC(a, smem, blockIdx.x);
}
__global__ __launch_bounds__(256) void k_tk(MegaArgs a) {
  __shared__ __align__(16) char smem[39104];
  tk_body(blockIdx.x, smem, a.attn, a.mid_bf, a.tbuf);
}
__global__ __launch_bounds__(256) void k_vproj(MegaArgs a) {
  __shared__ __align__(16) char smem[12288];
  vproj_body(blockIdx.x / 3, blockIdx.x % 3, smem, a.tbuf, a.Wconv, a.op_bf);
}
__global__ __launch_bounds__(256) void k_outk(MegaArgs a) {
  __shared__ __align__(16) char smem[16384];
  phaseF(a, smem, blockIdx.x);
}
__global__ __launch_bounds__(256) void k_red(MegaArgs a) {
  phaseG(a, blockIdx.x * 256 + threadIdx.x, gridDim.x * 256);
}

extern "C" void kernel_launch(void* const* d_in, const int* in_sizes, int n_in,
                              void* d_out, int out_size, void* d_ws, size_t ws_size,
                              hipStream_t stream) {
  (void)in_sizes; (void)n_in; (void)out_size; (void)ws_size;

  char* ws = (char*)d_ws;
  size_t off = 0;
  auto alloc = [&](size_t bytes) -> void* {
    void* p = (void*)(ws + off);
    off += (bytes + 255) & ~(size_t)255;
    return p;
  };

  MegaArgs a;
  a.x    = (const float*)d_in[0];
  a.ctx  = (const float*)d_in[1];
  a.Wq   = (const float*)d_in[2];
  a.Wk   = (const float*)d_in[3];
  a.Wv1  = (const float*)d_in[4];
  a.ln_g = (const float*)d_in[5];
  a.ln_b = (const float*)d_in[6];
  a.Wconv = (const float*)d_in[7];
  a.Wout = (const float*)d_in[8];
  a.out  = (float*)d_out;

  a.x_bf    = (short*)alloc((size_t)393216 * 2);
  a.ctx_bf  = (short*)alloc((size_t)1579008 * 2);
  a.wq_bf   = (short*)alloc((size_t)589824 * 2);
  a.wk_bf   = (short*)alloc((size_t)589824 * 2);
  a.wv1_bf  = (short*)alloc((size_t)3145728 * 2);
  a.wout_bf = (short*)alloc((size_t)589824 * 2);
  a.q_bf    = (short*)alloc((size_t)393216 * 2);
  a.k_bf    = (short*)alloc((size_t)1579008 * 2);
  a.mid_bf  = (short*)alloc((size_t)8421376 * 2);
  a.attn    = (float*)alloc((size_t)789504 * 4);
  a.tbuf    = (float*)alloc((size_t)196608 * 4);
  a.op_bf   = (short*)alloc((size_t)393216 * 2);
  a.part    = (float*)alloc((size_t)393216 * 8 * 4);

  // size the cooperative grid from actual occupancy (host-only queries; capture-safe,
  // deterministic across calls)
  int dev = 0;
  (void)hipGetDevice(&dev);
  int ncu = 256;
  if (hipDeviceGetAttribute(&ncu, hipDeviceAttributeMultiprocessorCount, dev) != hipSuccess || ncu <= 0)
    ncu = 256;
  int occ = 0;
  int grid = 256;
  if (hipOccupancyMaxActiveBlocksPerMultiprocessor(&occ, (const void*)mega, 256, 0) == hipSuccess && occ >= 1)
    grid = occ * ncu;
  if (grid > 768) grid = 768;

  void* kargs[] = { (void*)&a };
  hipError_t le = hipLaunchCooperativeKernel((const void*)mega, dim3(grid), dim3(256),
                                             kargs, 0, stream);
  if (le != hipSuccess) {
    // fallback: proven multi-kernel pipeline (deterministic partials, no atomics)
    k_cvt<<<dim3(2048), dim3(256), 0, stream>>>(a);
    k_gemm3<<<dim3(670), dim3(256), 0, stream>>>(a);
    k_lnattn<<<dim3(2104), dim3(256), 0, stream>>>(a);
    k_tk<<<dim3(512), dim3(256), 0, stream>>>(a);
    k_vproj<<<dim3(192), dim3(256), 0, stream>>>(a);
    k_outk<<<dim3(192), dim3(256), 0, stream>>>(a);
    k_red<<<dim3(384), dim3(256), 0, stream>>>(a);
  }
}

// Round 10
// 265.096 us; speedup vs baseline: 2.5081x; 2.5081x over previous
//
#include <hip/hip_runtime.h>

#define DEV __device__ __forceinline__

typedef __attribute__((ext_vector_type(8))) short sv8;   // 8 x bf16 bits
typedef __attribute__((ext_vector_type(4))) short sv4;
typedef __attribute__((ext_vector_type(4))) float f32x4;

// ---- bf16 helpers (bit-level, round-to-nearest-even) ----
DEV short f2bf(float f) {
  unsigned u = __float_as_uint(f);
  unsigned r = (u + 0x7fffu + ((u >> 16) & 1u)) >> 16;
  return (short)r;
}
DEV float bf2f(short s) {
  return __uint_as_float(((unsigned)(unsigned short)s) << 16);
}

// ---- async global -> LDS, 16B per lane. LDS dest = wave-uniform base + lane*16 ----
DEV void gload16(const void* g, void* l) {
  __builtin_amdgcn_global_load_lds((const __attribute__((address_space(1))) void*)g,
                                   (__attribute__((address_space(3))) void*)l, 16, 0, 0);
}

struct Args {
  const float *x, *ctx, *Wq, *Wk, *Wv1, *ln_g, *ln_b, *Wconv, *Wout;
  short *x_bf, *ctx_bf, *wq_bf, *wk_bf, *wv1_bf, *wout_bf;
  short *q_bf, *k_bf, *mid_bf, *op_bf;
  float *attn, *stats, *out;
};

// ================= K1: fp32 -> bf16 for 6 tensors, grid-stride =================
__global__ __launch_bounds__(256) void k_cvt(Args a) {
  const int gtid = blockIdx.x * 256 + threadIdx.x;
  const int T = gridDim.x * 256;
  for (int i = gtid; i < 1721856; i += T) {   // float4 units, cumulative ends
    const float* s; short* d; int base;
    if      (i < 98304)   { s = a.x;    d = a.x_bf;    base = 0; }
    else if (i < 493056)  { s = a.ctx;  d = a.ctx_bf;  base = 98304; }
    else if (i < 640512)  { s = a.Wq;   d = a.wq_bf;   base = 493056; }
    else if (i < 787968)  { s = a.Wk;   d = a.wk_bf;   base = 640512; }
    else if (i < 1574400) { s = a.Wv1;  d = a.wv1_bf;  base = 787968; }
    else                  { s = a.Wout; d = a.wout_bf; base = 1574400; }
    int j = i - base;
    float4 v = ((const float4*)s)[j];
    sv4 o = { f2bf(v.x), f2bf(v.y), f2bf(v.z), f2bf(v.w) };
    ((sv4*)d)[j] = o;
  }
}

// ===== NT GEMM tile: C[M,N]=A[M,K]*B[N,K]^T, 128x128, BK=32, 2-phase dbuf ======
// 16B-slot XOR swizzle both-sides (write: inverse-swizzled global source; read: XOR).
// MODE: 1 = bf16 store, 2 = f32 atomicAdd (split-K).
template <int MODE, int SPLITK>
DEV void gemm_tile(const short* __restrict__ A, const short* __restrict__ B,
                   void* __restrict__ C, int M, int N, int K,
                   int bm, int bn, int ks) {
  __shared__ __align__(16) short As[2][4096];
  __shared__ __align__(16) short Bs[2][4096];
  const int tid = threadIdx.x;
  const int wave = tid >> 6, lane = tid & 63;
  const int wr = wave >> 1, wc = wave & 1;
  const int row0 = bm * 128, col0 = bn * 128;
  const int rsel = lane & 15;
  const int Am = M - 1, Bm = N - 1;
  const int lr = lane >> 2;
  const int c8 = ((lane & 3) ^ ((lane >> 2) & 3)) * 8;  // inverse-swizzled source slot
  const int Ksl = K / SPLITK;
  const int kbase = ks * Ksl;
  const int nt = Ksl / 32;

  const f32x4 z = {0.f, 0.f, 0.f, 0.f};
  f32x4 acc[4][4];
#pragma unroll
  for (int m = 0; m < 4; ++m)
#pragma unroll
    for (int n = 0; n < 4; ++n) acc[m][n] = z;

  auto stage = [&](int t, int buf) {
    int k0 = kbase + t * 32;
#pragma unroll
    for (int s = 0; s < 2; ++s) {
      int chunk = s * 4 + wave;            // wave-uniform LDS chunk
      int rr = chunk * 16 + lr;
      int gr = row0 + rr; if (gr > Am) gr = Am;
      gload16(A + (size_t)gr * K + k0 + c8, &As[buf][chunk * 512]);
      int gc = col0 + rr; if (gc > Bm) gc = Bm;
      gload16(B + (size_t)gc * K + k0 + c8, &Bs[buf][chunk * 512]);
    }
  };

  stage(0, 0);
  __syncthreads();
  const int ko = (((lane >> 4) ^ (rsel & 3)) * 8);  // swizzled read slot

  for (int t = 0; t < nt; ++t) {
    int cur = t & 1;
    if (t + 1 < nt) stage(t + 1, cur ^ 1);
    sv8 a[4], b[4];
#pragma unroll
    for (int m = 0; m < 4; ++m)
      a[m] = *(const sv8*)(&As[cur][(wr * 64 + m * 16 + rsel) * 32 + ko]);
#pragma unroll
    for (int n = 0; n < 4; ++n)
      b[n] = *(const sv8*)(&Bs[cur][(wc * 64 + n * 16 + rsel) * 32 + ko]);
#pragma unroll
    for (int m = 0; m < 4; ++m)
#pragma unroll
      for (int n = 0; n < 4; ++n)
        acc[m][n] = __builtin_amdgcn_mfma_f32_16x16x32_bf16(a[m], b[n], acc[m][n], 0, 0, 0);
    __syncthreads();
  }

  const int cc = lane & 15, cr = (lane >> 4) * 4;
#pragma unroll
  for (int m = 0; m < 4; ++m)
#pragma unroll
    for (int n = 0; n < 4; ++n) {
      int c = col0 + wc * 64 + n * 16 + cc;
#pragma unroll
      for (int j = 0; j < 4; ++j) {
        int r = row0 + wr * 64 + m * 16 + cr + j;
        if (r < M && c < N) {
          float v = acc[m][n][j];
          if (MODE == 1) ((short*)C)[(size_t)r * N + c] = f2bf(v);
          else           atomicAdd(&((float*)C)[(size_t)r * N + c], v);
        }
      }
    }
}

// ================= K2: q + k + mid GEMMs, 670 blocks =================
__global__ __launch_bounds__(256) void k_gemm3(Args a) {
  const int bid = blockIdx.x;
  const short *A_, *B_; short* C_; int M_, nb_, local;
  if (bid < 24)       { A_ = a.x_bf;   B_ = a.wq_bf;  C_ = a.q_bf;   M_ = 512;  nb_ = 6;  local = bid; }
  else if (bid < 126) { A_ = a.ctx_bf; B_ = a.wk_bf;  C_ = a.k_bf;   M_ = 2056; nb_ = 6;  local = bid - 24; }
  else                { A_ = a.ctx_bf; B_ = a.wv1_bf; C_ = a.mid_bf; M_ = 2056; nb_ = 32; local = bid - 126; }
  gemm_tile<1, 1>(A_, B_, C_, M_, nb_ * 128, 768, local / nb_, local % nb_, 0);
}

// ================= K3: attention (0-47) + LN stats (48-304) + zero d_out (305-688) ====
DEV void attn_body(int bh, const short* __restrict__ qb, const short* __restrict__ kb,
                   float* __restrict__ attn, float (*wred)[64]) {
  const int b = bh / 6, h = bh % 6;
  const int tid = threadIdx.x, wave = tid >> 6, lane = tid & 63;
  const int rsel = lane & 15, koff = (lane >> 4) * 8;
  const int rhi = (lane >> 4) * 4;

  const f32x4 z = {0.f, 0.f, 0.f, 0.f};
  f32x4 acc[4][5];
#pragma unroll
  for (int m = 0; m < 4; ++m)
#pragma unroll
    for (int i = 0; i < 5; ++i) acc[m][i] = z;

#pragma unroll
  for (int k0 = 0; k0 < 128; k0 += 32) {
    sv8 a[4];
#pragma unroll
    for (int m = 0; m < 4; ++m)
      a[m] = *(const sv8*)(qb + (size_t)(b * 64 + m * 16 + rsel) * 768 + h * 128 + k0 + koff);
#pragma unroll
    for (int i = 0; i < 5; ++i) {
      int nf = wave + i * 4;
      if (nf > 16) continue;
      int j = nf * 16 + rsel; if (j > 256) j = 256;
      sv8 bf = *(const sv8*)(kb + (size_t)(b * 257 + j) * 768 + h * 128 + k0 + koff);
#pragma unroll
      for (int m = 0; m < 4; ++m)
        acc[m][i] = __builtin_amdgcn_mfma_f32_16x16x32_bf16(a[m], bf, acc[m][i], 0, 0, 0);
    }
  }
  const float S2 = 0.08838834764831845f;  // 1/sqrt(128)
#pragma unroll
  for (int m = 0; m < 4; ++m)
#pragma unroll
    for (int i = 0; i < 5; ++i) {
      int col = (wave + i * 4) * 16 + rsel;
      bool valid = col < 257;
#pragma unroll
      for (int j = 0; j < 4; ++j)
        acc[m][i][j] = valid ? acc[m][i][j] * S2 : -1e30f;
    }
  float mx[4][4];
#pragma unroll
  for (int m = 0; m < 4; ++m)
#pragma unroll
    for (int j = 0; j < 4; ++j) {
      float pm = acc[m][0][j];
#pragma unroll
      for (int i = 1; i < 5; ++i) pm = fmaxf(pm, acc[m][i][j]);
      pm = fmaxf(pm, __shfl_xor(pm, 1));
      pm = fmaxf(pm, __shfl_xor(pm, 2));
      pm = fmaxf(pm, __shfl_xor(pm, 4));
      pm = fmaxf(pm, __shfl_xor(pm, 8));
      mx[m][j] = pm;
      if (rsel == 0) wred[wave][m * 16 + rhi + j] = pm;
    }
  __syncthreads();
#pragma unroll
  for (int m = 0; m < 4; ++m)
#pragma unroll
    for (int j = 0; j < 4; ++j) {
      int row = m * 16 + rhi + j;
      mx[m][j] = fmaxf(fmaxf(wred[0][row], wred[1][row]), fmaxf(wred[2][row], wred[3][row]));
    }
  __syncthreads();
  float inv[4][4];
#pragma unroll
  for (int m = 0; m < 4; ++m)
#pragma unroll
    for (int j = 0; j < 4; ++j) {
      float ps = 0.f;
#pragma unroll
      for (int i = 0; i < 5; ++i) {
        float e = __expf(acc[m][i][j] - mx[m][j]);
        acc[m][i][j] = e;
        ps += e;
      }
      ps += __shfl_xor(ps, 1);
      ps += __shfl_xor(ps, 2);
      ps += __shfl_xor(ps, 4);
      ps += __shfl_xor(ps, 8);
      if (rsel == 0) wred[wave][m * 16 + rhi + j] = ps;
    }
  __syncthreads();
  float* base = attn + (size_t)bh * 64 * 257;
#pragma unroll
  for (int m = 0; m < 4; ++m)
#pragma unroll
    for (int j = 0; j < 4; ++j) {
      int row = m * 16 + rhi + j;
      float tot = wred[0][row] + wred[1][row] + wred[2][row] + wred[3][row];
      inv[m][j] = 1.f / tot;
    }
#pragma unroll
  for (int m = 0; m < 4; ++m)
#pragma unroll
    for (int i = 0; i < 5; ++i) {
      int nf = wave + i * 4;
      if (nf > 16) continue;
      int col = nf * 16 + rsel;
      if (col < 257) {
#pragma unroll
        for (int j = 0; j < 4; ++j)
          base[(size_t)(m * 16 + rhi + j) * 257 + col] = acc[m][i][j] * inv[m][j];
      }
    }
}

__global__ __launch_bounds__(256) void k_attn_stats(Args a) {
  __shared__ float wred[4][64];
  const int bid = blockIdx.x, tid = threadIdx.x;
  if (bid < 48) {
    attn_body(bid, a.q_bf, a.k_bf, a.attn, wred);
  } else if (bid < 305) {
    // LN stats: 8 rows per block, 32 lanes per row (lane-halves of each wave)
    const int row = (bid - 48) * 8 + (tid >> 5);
    const int lane32 = tid & 31;
    const short* p = a.mid_bf + (size_t)row * 4096 + lane32 * 128;
    float s = 0.f, ss = 0.f;
#pragma unroll
    for (int i = 0; i < 16; ++i) {
      sv8 v = *(const sv8*)(p + i * 8);
#pragma unroll
      for (int j = 0; j < 8; ++j) { float f = bf2f(v[j]); s += f; ss += f * f; }
    }
#pragma unroll
    for (int off = 16; off; off >>= 1) { s += __shfl_xor(s, off); ss += __shfl_xor(ss, off); }
    if (lane32 == 0) {
      const float inv_n = 1.0f / 4096.0f;
      float mu = s * inv_n;
      float var = ss * inv_n - mu * mu;
      a.stats[row * 2]     = mu;
      a.stats[row * 2 + 1] = rsqrtf(var + 1e-5f);
    }
  } else {
    // zero d_out (atomic split-K target): 384 blocks x 256 float4
    int i = (bid - 305) * 256 + tid;
    ((float4*)a.out)[i] = make_float4(0.f, 0.f, 0.f, 0.f);
  }
}

// ======== K4: fused t-contraction (with on-the-fly LN) + Wconv expansion ========
// One block per (q, b-half). t[h][r] = sum_j attn*(mid-mu)*rstd*g + beta  (folded),
// then op[b,q,d] = sum_r t[h(d)][r] * Wconv[q,d,r].
__global__ __launch_bounds__(256) void k_tkvp(Args a) {
  __shared__ short ms[257][64];        // 32896 B: mid slice for current b
  __shared__ float asl[6][257];        // 6168 B: raw attn rows for current b
  __shared__ float st[514];            // 2056 B: {mu,rstd} per j for current b
  __shared__ float tsl[4][6][64];      // 6144 B: t for 4 b's
  __shared__ float c0S[6][2];          // c0[h], S[h]
  __shared__ float gl[64], bl[64];     // LN gamma/beta slice for this q
  const int q = blockIdx.x >> 1, half = blockIdx.x & 1;
  const int tid = threadIdx.x;

  if (tid < 64) {
    gl[tid] = a.ln_g[q * 64 + tid];
    bl[tid] = a.ln_b[q * 64 + tid];
  }

  for (int bb = 0; bb < 4; ++bb) {
    const int b = half * 4 + bb;
    for (int lin = tid; lin < 257 * 8; lin += 256) {
      int j = lin >> 3, seg = (lin & 7) * 8;
      *(sv8*)(&ms[j][seg]) = *(const sv8*)(a.mid_bf + (size_t)(b * 257 + j) * 4096 + q * 64 + seg);
    }
    for (int idx = tid; idx < 1542; idx += 256) {
      int h = idx / 257, j = idx - h * 257;
      asl[h][j] = a.attn[((size_t)(b * 6 + h) * 64 + q) * 257 + j];
    }
    for (int j2 = tid; j2 < 514; j2 += 256) st[j2] = a.stats[b * 257 * 2 + j2];
    __syncthreads();
    if (tid < 6) {
      float c0 = 0.f, S = 0.f;
      for (int j = 0; j < 257; ++j) {
        float av = asl[tid][j];
        S += av;
        c0 += av * st[j * 2 + 1] * st[j * 2];
      }
      c0S[tid][0] = c0; c0S[tid][1] = S;
    }
    __syncthreads();
    for (int idx = tid; idx < 384; idx += 256) {
      int h = idx >> 6, r = idx & 63;
      float s1 = 0.f;
#pragma unroll 4
      for (int j = 0; j < 257; ++j)
        s1 += asl[h][j] * st[j * 2 + 1] * bf2f(ms[j][r]);
      tsl[bb][h][r] = gl[r] * (s1 - c0S[h][0]) + bl[r] * c0S[h][1];
    }
    __syncthreads();   // protect ms/asl/st before next bb overwrites
  }

  // vproj: 3 chunks of 256 d's
#pragma unroll
  for (int chunk = 0; chunk < 3; ++chunk) {
    const int d = chunk * 256 + tid;
    const int h = d >> 7;  // wave-uniform
    const float4* w4 = (const float4*)(a.Wconv + ((size_t)q * 768 + d) * 64);
    float facc[4] = {0.f, 0.f, 0.f, 0.f};
#pragma unroll
    for (int r4 = 0; r4 < 16; ++r4) {
      float4 w = w4[r4];
#pragma unroll
      for (int bb = 0; bb < 4; ++bb) {
        facc[bb] += w.x * tsl[bb][h][r4 * 4 + 0];
        facc[bb] += w.y * tsl[bb][h][r4 * 4 + 1];
        facc[bb] += w.z * tsl[bb][h][r4 * 4 + 2];
        facc[bb] += w.w * tsl[bb][h][r4 * 4 + 3];
      }
    }
#pragma unroll
    for (int bb = 0; bb < 4; ++bb)
      a.op_bf[((size_t)((half * 4 + bb) * 64 + q)) * 768 + d] = f2bf(facc[bb]);
  }
}

// ================= K5: out = op @ Wout^T, split-K=4 atomic into zeroed d_out ====
__global__ __launch_bounds__(256) void k_outk(Args a) {
  gemm_tile<2, 4>(a.op_bf, a.wout_bf, a.out, 512, 768, 768,
                  blockIdx.x, blockIdx.y, blockIdx.z);
}

extern "C" void kernel_launch(void* const* d_in, const int* in_sizes, int n_in,
                              void* d_out, int out_size, void* d_ws, size_t ws_size,
                              hipStream_t stream) {
  (void)in_sizes; (void)n_in; (void)out_size; (void)ws_size;

  char* ws = (char*)d_ws;
  size_t off = 0;
  auto alloc = [&](size_t bytes) -> void* {
    void* p = (void*)(ws + off);
    off += (bytes + 255) & ~(size_t)255;
    return p;
  };

  Args a;
  a.x    = (const float*)d_in[0];
  a.ctx  = (const float*)d_in[1];
  a.Wq   = (const float*)d_in[2];
  a.Wk   = (const float*)d_in[3];
  a.Wv1  = (const float*)d_in[4];
  a.ln_g = (const float*)d_in[5];
  a.ln_b = (const float*)d_in[6];
  a.Wconv = (const float*)d_in[7];
  a.Wout = (const float*)d_in[8];
  a.out  = (float*)d_out;

  a.x_bf    = (short*)alloc((size_t)393216 * 2);
  a.ctx_bf  = (short*)alloc((size_t)1579008 * 2);
  a.wq_bf   = (short*)alloc((size_t)589824 * 2);
  a.wk_bf   = (short*)alloc((size_t)589824 * 2);
  a.wv1_bf  = (short*)alloc((size_t)3145728 * 2);
  a.wout_bf = (short*)alloc((size_t)589824 * 2);
  a.q_bf    = (short*)alloc((size_t)393216 * 2);
  a.k_bf    = (short*)alloc((size_t)1579008 * 2);
  a.mid_bf  = (short*)alloc((size_t)8421376 * 2);
  a.attn    = (float*)alloc((size_t)789504 * 4);
  a.stats   = (float*)alloc((size_t)4112 * 4);
  a.op_bf   = (short*)alloc((size_t)393216 * 2);

  // 1. fp32 -> bf16 (grid-stride)
  k_cvt<<<dim3(2048), dim3(256), 0, stream>>>(a);
  // 2. q + k + mid GEMMs
  k_gemm3<<<dim3(670), dim3(256), 0, stream>>>(a);
  // 3. attention + LN stats + zero d_out
  k_attn_stats<<<dim3(689), dim3(256), 0, stream>>>(a);
  // 4. fused t-contraction (LN on the fly) + Wconv expansion
  k_tkvp<<<dim3(128), dim3(256), 0, stream>>>(a);
  // 5. out GEMM, split-K=4 atomic
  k_outk<<<dim3(4, 6, 4), dim3(256), 0, stream>>>(a);
}

// Round 11
// 172.545 us; speedup vs baseline: 3.8535x; 1.5364x over previous
//
#include <hip/hip_runtime.h>

#define DEV __device__ __forceinline__

typedef __attribute__((ext_vector_type(8))) short sv8;   // 8 x bf16 bits
typedef __attribute__((ext_vector_type(4))) short sv4;
typedef __attribute__((ext_vector_type(4))) float f32x4;

// ---- bf16 helpers (bit-level, round-to-nearest-even) ----
DEV short f2bf(float f) {
  unsigned u = __float_as_uint(f);
  unsigned r = (u + 0x7fffu + ((u >> 16) & 1u)) >> 16;
  return (short)r;
}
DEV float bf2f(short s) {
  return __uint_as_float(((unsigned)(unsigned short)s) << 16);
}

// ---- async global -> LDS, 16B per lane. LDS dest = wave-uniform base + lane*16 ----
DEV void gload16(const void* g, void* l) {
  __builtin_amdgcn_global_load_lds((const __attribute__((address_space(1))) void*)g,
                                   (__attribute__((address_space(3))) void*)l, 16, 0, 0);
}

struct Args {
  const float *x, *ctx, *Wq, *Wk, *Wv1, *ln_g, *ln_b, *Wconv, *Wout;
  short *x_bf, *ctx_bf, *wq_bf, *wk_bf, *wv1_bf, *wout_bf;
  short *q_bf, *k_bf, *mid_bf, *op_bf;
  float *attn, *stats, *tbuf, *out;
};

// ================= K1: fp32 -> bf16 for 6 tensors, grid-stride =================
__global__ __launch_bounds__(256) void k_cvt(Args a) {
  const int gtid = blockIdx.x * 256 + threadIdx.x;
  const int T = gridDim.x * 256;
  for (int i = gtid; i < 1721856; i += T) {   // float4 units, cumulative ends
    const float* s; short* d; int base;
    if      (i < 98304)   { s = a.x;    d = a.x_bf;    base = 0; }
    else if (i < 493056)  { s = a.ctx;  d = a.ctx_bf;  base = 98304; }
    else if (i < 640512)  { s = a.Wq;   d = a.wq_bf;   base = 493056; }
    else if (i < 787968)  { s = a.Wk;   d = a.wk_bf;   base = 640512; }
    else if (i < 1574400) { s = a.Wv1;  d = a.wv1_bf;  base = 787968; }
    else                  { s = a.Wout; d = a.wout_bf; base = 1574400; }
    int j = i - base;
    float4 v = ((const float4*)s)[j];
    sv4 o = { f2bf(v.x), f2bf(v.y), f2bf(v.z), f2bf(v.w) };
    ((sv4*)d)[j] = o;
  }
}

// ===== NT GEMM tile: C[M,N]=A[M,K]*B[N,K]^T, 128x128, BK=32, 2-phase dbuf ======
// MODE: 1 = bf16 store, 2 = f32 atomicAdd (split-K).
template <int MODE, int SPLITK>
DEV void gemm_tile(const short* __restrict__ A, const short* __restrict__ B,
                   void* __restrict__ C, int M, int N, int K,
                   int bm, int bn, int ks) {
  __shared__ __align__(16) short As[2][4096];
  __shared__ __align__(16) short Bs[2][4096];
  const int tid = threadIdx.x;
  const int wave = tid >> 6, lane = tid & 63;
  const int wr = wave >> 1, wc = wave & 1;
  const int row0 = bm * 128, col0 = bn * 128;
  const int rsel = lane & 15;
  const int Am = M - 1, Bm = N - 1;
  const int lr = lane >> 2;
  const int c8 = ((lane & 3) ^ ((lane >> 2) & 3)) * 8;  // inverse-swizzled source slot
  const int Ksl = K / SPLITK;
  const int kbase = ks * Ksl;
  const int nt = Ksl / 32;

  const f32x4 z = {0.f, 0.f, 0.f, 0.f};
  f32x4 acc[4][4];
#pragma unroll
  for (int m = 0; m < 4; ++m)
#pragma unroll
    for (int n = 0; n < 4; ++n) acc[m][n] = z;

  auto stage = [&](int t, int buf) {
    int k0 = kbase + t * 32;
#pragma unroll
    for (int s = 0; s < 2; ++s) {
      int chunk = s * 4 + wave;            // wave-uniform LDS chunk
      int rr = chunk * 16 + lr;
      int gr = row0 + rr; if (gr > Am) gr = Am;
      gload16(A + (size_t)gr * K + k0 + c8, &As[buf][chunk * 512]);
      int gc = col0 + rr; if (gc > Bm) gc = Bm;
      gload16(B + (size_t)gc * K + k0 + c8, &Bs[buf][chunk * 512]);
    }
  };

  stage(0, 0);
  __syncthreads();
  const int ko = (((lane >> 4) ^ (rsel & 3)) * 8);  // swizzled read slot

  for (int t = 0; t < nt; ++t) {
    int cur = t & 1;
    if (t + 1 < nt) stage(t + 1, cur ^ 1);
    sv8 a[4], b[4];
#pragma unroll
    for (int m = 0; m < 4; ++m)
      a[m] = *(const sv8*)(&As[cur][(wr * 64 + m * 16 + rsel) * 32 + ko]);
#pragma unroll
    for (int n = 0; n < 4; ++n)
      b[n] = *(const sv8*)(&Bs[cur][(wc * 64 + n * 16 + rsel) * 32 + ko]);
#pragma unroll
    for (int m = 0; m < 4; ++m)
#pragma unroll
      for (int n = 0; n < 4; ++n)
        acc[m][n] = __builtin_amdgcn_mfma_f32_16x16x32_bf16(a[m], b[n], acc[m][n], 0, 0, 0);
    __syncthreads();
  }

  const int cc = lane & 15, cr = (lane >> 4) * 4;
#pragma unroll
  for (int m = 0; m < 4; ++m)
#pragma unroll
    for (int n = 0; n < 4; ++n) {
      int c = col0 + wc * 64 + n * 16 + cc;
#pragma unroll
      for (int j = 0; j < 4; ++j) {
        int r = row0 + wr * 64 + m * 16 + cr + j;
        if (r < M && c < N) {
          float v = acc[m][n][j];
          if (MODE == 1) ((short*)C)[(size_t)r * N + c] = f2bf(v);
          else           atomicAdd(&((float*)C)[(size_t)r * N + c], v);
        }
      }
    }
}

// ================= K2: q + k + mid GEMMs, 670 blocks =================
__global__ __launch_bounds__(256) void k_gemm3(Args a) {
  const int bid = blockIdx.x;
  const short *A_, *B_; short* C_; int M_, nb_, local;
  if (bid < 24)       { A_ = a.x_bf;   B_ = a.wq_bf;  C_ = a.q_bf;   M_ = 512;  nb_ = 6;  local = bid; }
  else if (bid < 126) { A_ = a.ctx_bf; B_ = a.wk_bf;  C_ = a.k_bf;   M_ = 2056; nb_ = 6;  local = bid - 24; }
  else                { A_ = a.ctx_bf; B_ = a.wv1_bf; C_ = a.mid_bf; M_ = 2056; nb_ = 32; local = bid - 126; }
  gemm_tile<1, 1>(A_, B_, C_, M_, nb_ * 128, 768, local / nb_, local % nb_, 0);
}

// ========== K3: attention (0-47) + LN stats (48-304) + zero d_out (305-688) =====
DEV void attn_body(int bh, const short* __restrict__ qb, const short* __restrict__ kb,
                   float* __restrict__ attn, float (*wred)[64]) {
  const int b = bh / 6, h = bh % 6;
  const int tid = threadIdx.x, wave = tid >> 6, lane = tid & 63;
  const int rsel = lane & 15, koff = (lane >> 4) * 8;
  const int rhi = (lane >> 4) * 4;

  const f32x4 z = {0.f, 0.f, 0.f, 0.f};
  f32x4 acc[4][5];
#pragma unroll
  for (int m = 0; m < 4; ++m)
#pragma unroll
    for (int i = 0; i < 5; ++i) acc[m][i] = z;

#pragma unroll
  for (int k0 = 0; k0 < 128; k0 += 32) {
    sv8 a[4];
#pragma unroll
    for (int m = 0; m < 4; ++m)
      a[m] = *(const sv8*)(qb + (size_t)(b * 64 + m * 16 + rsel) * 768 + h * 128 + k0 + koff);
#pragma unroll
    for (int i = 0; i < 5; ++i) {
      int nf = wave + i * 4;
      if (nf > 16) continue;
      int j = nf * 16 + rsel; if (j > 256) j = 256;
      sv8 bf = *(const sv8*)(kb + (size_t)(b * 257 + j) * 768 + h * 128 + k0 + koff);
#pragma unroll
      for (int m = 0; m < 4; ++m)
        acc[m][i] = __builtin_amdgcn_mfma_f32_16x16x32_bf16(a[m], bf, acc[m][i], 0, 0, 0);
    }
  }
  const float S2 = 0.08838834764831845f;  // 1/sqrt(128)
#pragma unroll
  for (int m = 0; m < 4; ++m)
#pragma unroll
    for (int i = 0; i < 5; ++i) {
      int col = (wave + i * 4) * 16 + rsel;
      bool valid = col < 257;
#pragma unroll
      for (int j = 0; j < 4; ++j)
        acc[m][i][j] = valid ? acc[m][i][j] * S2 : -1e30f;
    }
  float mx[4][4];
#pragma unroll
  for (int m = 0; m < 4; ++m)
#pragma unroll
    for (int j = 0; j < 4; ++j) {
      float pm = acc[m][0][j];
#pragma unroll
      for (int i = 1; i < 5; ++i) pm = fmaxf(pm, acc[m][i][j]);
      pm = fmaxf(pm, __shfl_xor(pm, 1));
      pm = fmaxf(pm, __shfl_xor(pm, 2));
      pm = fmaxf(pm, __shfl_xor(pm, 4));
      pm = fmaxf(pm, __shfl_xor(pm, 8));
      mx[m][j] = pm;
      if (rsel == 0) wred[wave][m * 16 + rhi + j] = pm;
    }
  __syncthreads();
#pragma unroll
  for (int m = 0; m < 4; ++m)
#pragma unroll
    for (int j = 0; j < 4; ++j) {
      int row = m * 16 + rhi + j;
      mx[m][j] = fmaxf(fmaxf(wred[0][row], wred[1][row]), fmaxf(wred[2][row], wred[3][row]));
    }
  __syncthreads();
  float inv[4][4];
#pragma unroll
  for (int m = 0; m < 4; ++m)
#pragma unroll
    for (int j = 0; j < 4; ++j) {
      float ps = 0.f;
#pragma unroll
      for (int i = 0; i < 5; ++i) {
        float e = __expf(acc[m][i][j] - mx[m][j]);
        acc[m][i][j] = e;
        ps += e;
      }
      ps += __shfl_xor(ps, 1);
      ps += __shfl_xor(ps, 2);
      ps += __shfl_xor(ps, 4);
      ps += __shfl_xor(ps, 8);
      if (rsel == 0) wred[wave][m * 16 + rhi + j] = ps;
    }
  __syncthreads();
  float* base = attn + (size_t)bh * 64 * 257;
#pragma unroll
  for (int m = 0; m < 4; ++m)
#pragma unroll
    for (int j = 0; j < 4; ++j) {
      int row = m * 16 + rhi + j;
      float tot = wred[0][row] + wred[1][row] + wred[2][row] + wred[3][row];
      inv[m][j] = 1.f / tot;
    }
#pragma unroll
  for (int m = 0; m < 4; ++m)
#pragma unroll
    for (int i = 0; i < 5; ++i) {
      int nf = wave + i * 4;
      if (nf > 16) continue;
      int col = nf * 16 + rsel;
      if (col < 257) {
#pragma unroll
        for (int j = 0; j < 4; ++j)
          base[(size_t)(m * 16 + rhi + j) * 257 + col] = acc[m][i][j] * inv[m][j];
      }
    }
}

__global__ __launch_bounds__(256) void k_attn_stats(Args a) {
  __shared__ float wred[4][64];
  const int bid = blockIdx.x, tid = threadIdx.x;
  if (bid < 48) {
    attn_body(bid, a.q_bf, a.k_bf, a.attn, wred);
  } else if (bid < 305) {
    // LN stats: 8 rows per block, 32 lanes per row
    const int row = (bid - 48) * 8 + (tid >> 5);
    const int lane32 = tid & 31;
    const short* p = a.mid_bf + (size_t)row * 4096 + lane32 * 128;
    float s = 0.f, ss = 0.f;
#pragma unroll
    for (int i = 0; i < 16; ++i) {
      sv8 v = *(const sv8*)(p + i * 8);
#pragma unroll
      for (int j = 0; j < 8; ++j) { float f = bf2f(v[j]); s += f; ss += f * f; }
    }
#pragma unroll
    for (int off = 16; off; off >>= 1) { s += __shfl_xor(s, off); ss += __shfl_xor(ss, off); }
    if (lane32 == 0) {
      const float inv_n = 1.0f / 4096.0f;
      float mu = s * inv_n;
      float var = ss * inv_n - mu * mu;
      a.stats[row * 2]     = mu;
      a.stats[row * 2 + 1] = rsqrtf(var + 1e-5f);
    }
  } else {
    // zero d_out (atomic split-K target): 384 blocks x 256 float4
    int i = (bid - 305) * 256 + tid;
    ((float4*)a.out)[i] = make_float4(0.f, 0.f, 0.f, 0.f);
  }
}

// ========== K4: t[b,h,q,r] with LN folded; one block per (b,q), all lanes busy ====
// t = g[r]*(sum_j w[h][j]*mid[j][r] - c0[h]) + beta[r]*S[h],
//   w[h][j] = attn*rstd[j], c0[h] = sum_j w*mu[j], S[h] = sum_j attn.
__global__ __launch_bounds__(256) void k_tk(Args a) {
  __shared__ short ms[257][64];     // 32896 B
  __shared__ float w[6][257];       // 6168 B
  __shared__ float mu[257], rs[257];
  __shared__ float redC[6][4], redS[6][4];
  const int bq = blockIdx.x;
  const int b = bq >> 6, q = bq & 63;
  const int tid = threadIdx.x, wave = tid >> 6;

  // stage mid slice + stats
  for (int lin = tid; lin < 257 * 8; lin += 256) {
    int j = lin >> 3, seg = (lin & 7) * 8;
    *(sv8*)(&ms[j][seg]) = *(const sv8*)(a.mid_bf + (size_t)(b * 257 + j) * 4096 + q * 64 + seg);
  }
  for (int j = tid; j < 257; j += 256) {
    mu[j] = a.stats[(b * 257 + j) * 2];
    rs[j] = a.stats[(b * 257 + j) * 2 + 1];
  }
  __syncthreads();

  // w + per-h partial c0/S (static h indexing -> registers)
  float pc0[6] = {0.f, 0.f, 0.f, 0.f, 0.f, 0.f};
  float pS[6]  = {0.f, 0.f, 0.f, 0.f, 0.f, 0.f};
  for (int j = tid; j < 257; j += 256) {
    float rsj = rs[j], muj = mu[j];
#pragma unroll
    for (int h = 0; h < 6; ++h) {
      float av = a.attn[((size_t)(b * 6 + h) * 64 + q) * 257 + j];  // coalesced over tid
      float wv = av * rsj;
      w[h][j] = wv;
      pS[h] += av;
      pc0[h] += wv * muj;
    }
  }
#pragma unroll
  for (int h = 0; h < 6; ++h) {
#pragma unroll
    for (int off = 32; off; off >>= 1) {
      pc0[h] += __shfl_xor(pc0[h], off);
      pS[h]  += __shfl_xor(pS[h], off);
    }
    if ((tid & 63) == 0) { redC[h][wave] = pc0[h]; redS[h][wave] = pS[h]; }
  }
  __syncthreads();

  // t-loop: 384 (h,r) items over 256 threads, 4 independent accumulators
  for (int idx = tid; idx < 384; idx += 256) {
    const int h = idx >> 6, r = idx & 63;
    float s0 = 0.f, s1 = 0.f, s2 = 0.f, s3 = 0.f;
    for (int j = 0; j < 256; j += 4) {
      s0 += w[h][j]     * bf2f(ms[j][r]);
      s1 += w[h][j + 1] * bf2f(ms[j + 1][r]);
      s2 += w[h][j + 2] * bf2f(ms[j + 2][r]);
      s3 += w[h][j + 3] * bf2f(ms[j + 3][r]);
    }
    float stot = (s0 + s1) + (s2 + s3) + w[h][256] * bf2f(ms[256][r]);
    float c0 = redC[h][0] + redC[h][1] + redC[h][2] + redC[h][3];
    float S  = redS[h][0] + redS[h][1] + redS[h][2] + redS[h][3];
    float out = a.ln_g[q * 64 + r] * (stot - c0) + a.ln_b[q * 64 + r] * S;
    a.tbuf[((size_t)(b * 6 + h) * 64 + q) * 64 + r] = out;
  }
}

// ========== K5: out_pre[b,q,d] = sum_r t[b,h(d),q,r]*Wconv[q,d,r]; (q, d-chunk) ====
__global__ __launch_bounds__(256) void k_vproj(Args a) {
  __shared__ float ts[48][64];
  const int q = blockIdx.x / 3, chunk = blockIdx.x % 3;
  const int tid = threadIdx.x;
  for (int lin = tid; lin < 48 * 64; lin += 256) {
    int bh = lin >> 6, r = lin & 63;
    ts[bh][r] = a.tbuf[((size_t)bh * 64 + q) * 64 + r];
  }
  __syncthreads();
  const int d = chunk * 256 + tid;
  const int h = d >> 7;  // wave-uniform
  const float4* w4 = (const float4*)(a.Wconv + ((size_t)q * 768 + d) * 64);
  float acc[8] = {0.f, 0.f, 0.f, 0.f, 0.f, 0.f, 0.f, 0.f};
#pragma unroll
  for (int r4 = 0; r4 < 16; ++r4) {
    float4 wv = w4[r4];
#pragma unroll
    for (int bb = 0; bb < 8; ++bb) {
      acc[bb] += wv.x * ts[bb * 6 + h][r4 * 4 + 0];
      acc[bb] += wv.y * ts[bb * 6 + h][r4 * 4 + 1];
      acc[bb] += wv.z * ts[bb * 6 + h][r4 * 4 + 2];
      acc[bb] += wv.w * ts[bb * 6 + h][r4 * 4 + 3];
    }
  }
#pragma unroll
  for (int bb = 0; bb < 8; ++bb)
    a.op_bf[((size_t)(bb * 64 + q)) * 768 + d] = f2bf(acc[bb]);
}

// ================= K6: out = op @ Wout^T, split-K=4 atomic into zeroed d_out ====
__global__ __launch_bounds__(256) void k_outk(Args a) {
  gemm_tile<2, 4>(a.op_bf, a.wout_bf, a.out, 512, 768, 768,
                  blockIdx.x, blockIdx.y, blockIdx.z);
}

extern "C" void kernel_launch(void* const* d_in, const int* in_sizes, int n_in,
                              void* d_out, int out_size, void* d_ws, size_t ws_size,
                              hipStream_t stream) {
  (void)in_sizes; (void)n_in; (void)out_size; (void)ws_size;

  char* ws = (char*)d_ws;
  size_t off = 0;
  auto alloc = [&](size_t bytes) -> void* {
    void* p = (void*)(ws + off);
    off += (bytes + 255) & ~(size_t)255;
    return p;
  };

  Args a;
  a.x    = (const float*)d_in[0];
  a.ctx  = (const float*)d_in[1];
  a.Wq   = (const float*)d_in[2];
  a.Wk   = (const float*)d_in[3];
  a.Wv1  = (const float*)d_in[4];
  a.ln_g = (const float*)d_in[5];
  a.ln_b = (const float*)d_in[6];
  a.Wconv = (const float*)d_in[7];
  a.Wout = (const float*)d_in[8];
  a.out  = (float*)d_out;

  a.x_bf    = (short*)alloc((size_t)393216 * 2);
  a.ctx_bf  = (short*)alloc((size_t)1579008 * 2);
  a.wq_bf   = (short*)alloc((size_t)589824 * 2);
  a.wk_bf   = (short*)alloc((size_t)589824 * 2);
  a.wv1_bf  = (short*)alloc((size_t)3145728 * 2);
  a.wout_bf = (short*)alloc((size_t)589824 * 2);
  a.q_bf    = (short*)alloc((size_t)393216 * 2);
  a.k_bf    = (short*)alloc((size_t)1579008 * 2);
  a.mid_bf  = (short*)alloc((size_t)8421376 * 2);
  a.attn    = (float*)alloc((size_t)789504 * 4);
  a.stats   = (float*)alloc((size_t)4112 * 4);
  a.tbuf    = (float*)alloc((size_t)196608 * 4);
  a.op_bf   = (short*)alloc((size_t)393216 * 2);

  // 1. fp32 -> bf16
  k_cvt<<<dim3(2048), dim3(256), 0, stream>>>(a);
  // 2. q + k + mid GEMMs
  k_gemm3<<<dim3(670), dim3(256), 0, stream>>>(a);
  // 3. attention + LN stats + zero d_out
  k_attn_stats<<<dim3(689), dim3(256), 0, stream>>>(a);
  // 4. t-contraction with folded LN (512 blocks, all-lane parallel)
  k_tk<<<dim3(512), dim3(256), 0, stream>>>(a);
  // 5. Wconv expansion
  k_vproj<<<dim3(192), dim3(256), 0, stream>>>(a);
  // 6. out GEMM, split-K=4 atomic
  k_outk<<<dim3(4, 6, 4), dim3(256), 0, stream>>>(a);
}